// Round 1
// baseline (160.357 us; speedup 1.0000x reference)
//
#include <hip/hip_runtime.h>
#include <math.h>

#define N_NUC 256
#define N_NB  1024
#define N_ENV 8
#define F0    32
#define F1    16
#define FEAT  256
#define CUTOFF 5.0f

// 8 pairs per chunk, 16 chunks -> 128 pairs per block -> 2048 blocks
constexpr int PPC    = 8;
constexpr int CHUNKS = 16;
constexpr int NBLOCKS = (N_NUC * N_NB) / (PPC * CHUNKS);  // 2048

__global__ __launch_bounds__(256) void moon_fused_kernel(
    const float* __restrict__ r_nb_ne,   // (256,1024,3)
    const float* __restrict__ R,         // (256,3)
    const float* __restrict__ ne_scales, // (256,8)
    const float* __restrict__ ne_kernel, // (256,4,32)
    const float* __restrict__ ne_bias,   // (256,32)
    const float* __restrict__ env_weight,// (8,32)
    const float* __restrict__ W_beta,    // (32,16)
    const float* __restrict__ W_gamma,   // (16,256)
    const float* __restrict__ W_edge,    // (4,256)
    const float* __restrict__ b_edge,    // (256)
    const float* __restrict__ z_n,       // (256,256)
    float* __restrict__ out)             // gamma (256,1024,256) ++ edge (256,1024,256)
{
    __shared__ float wbS[F0 * F1];       // 512 floats
    __shared__ float hS[PPC][F0 + 1];    // padded to kill bank conflicts
    __shared__ float betaS[PPC][F1];
    __shared__ float inpS[PPC][4];
    __shared__ float cutS[PPC];

    const int tid = threadIdx.x;
    const int n = blockIdx.x >> 3;                 // 8 blocks per nucleus
    const int e_base = (blockIdx.x & 7) * (PPC * CHUNKS);

    // ---- preload W_beta into LDS ----
    for (int i = tid; i < F0 * F1; i += 256) wbS[i] = W_beta[i];

    // ---- phase-A hoisted per-(n,k) registers ----
    const int k = tid & 31;
    const int g = tid >> 5;                        // group 0..7 -> pair within chunk
    const float K0 = ne_kernel[n * 128 + 0 * 32 + k];
    const float K1 = ne_kernel[n * 128 + 1 * 32 + k];
    const float K2 = ne_kernel[n * 128 + 2 * 32 + k];
    const float K3 = ne_kernel[n * 128 + 3 * 32 + k];
    const float bk = ne_bias[n * 32 + k];
    float ew[N_ENV], sc[N_ENV];
    #pragma unroll
    for (int v = 0; v < N_ENV; ++v) ew[v] = env_weight[v * 32 + k];
    #pragma unroll
    for (int v = 0; v < N_ENV; ++v) sc[v] = ne_scales[n * N_ENV + v];

    const float Rx = R[n * 3 + 0], Ry = R[n * 3 + 1], Rz = R[n * 3 + 2];

    // ---- phase-B hoisted registers: each thread owns 4 consecutive feats ----
    const int q  = tid >> 6;                       // pair sub-group 0..3
    const int f0 = (tid & 63) * 4;
    float4 wg4[F1];
    #pragma unroll
    for (int j = 0; j < F1; ++j)
        wg4[j] = *reinterpret_cast<const float4*>(&W_gamma[j * FEAT + f0]);
    float4 we4[4];
    #pragma unroll
    for (int c = 0; c < 4; ++c)
        we4[c] = *reinterpret_cast<const float4*>(&W_edge[c * FEAT + f0]);
    float4 zb4 = *reinterpret_cast<const float4*>(&z_n[n * FEAT + f0]);
    {
        float4 b4 = *reinterpret_cast<const float4*>(&b_edge[f0]);
        zb4.x += b4.x; zb4.y += b4.y; zb4.z += b4.z; zb4.w += b4.w;
    }

    float* __restrict__ gamma_out = out;
    float* __restrict__ edge_out  = out + (size_t)N_NUC * N_NB * FEAT;

    __syncthreads();  // wbS ready

    for (int chunk = 0; chunk < CHUNKS; ++chunk) {
        const int e0 = e_base + chunk * PPC;

        // ---- Phase A: per-pair h[32] (one 32-lane group per pair) ----
        {
            const int e = e0 + g;
            const size_t pr = (size_t)n * N_NB + e;
            const float rx = r_nb_ne[pr * 3 + 0];
            const float ry = r_nb_ne[pr * 3 + 1];
            const float rz = r_nb_ne[pr * 3 + 2];
            const float dx = rx - Rx, dy = ry - Ry, dz = rz - Rz;
            const float d = sqrtf(dx * dx + dy * dy + dz * dz);
            float env = 0.f;
            #pragma unroll
            for (int v = 0; v < N_ENV; ++v) env += expf(-d * sc[v]) * ew[v];
            const float hv = tanhf(d * K0 + dx * K1 + dy * K2 + dz * K3 + bk) * env;
            hS[g][k] = hv;
            if (k == 0) {
                const float x = d * (1.0f / CUTOFF);
                const float om = 1.0f - x;
                cutS[g] = (x < 1.0f) ? om * om * (1.0f + 2.0f * x) : 0.0f;
                const float l  = log1pf(d);
                const float li = l / d;
                inpS[g][0] = l;
                inpS[g][1] = dx * li;
                inpS[g][2] = dy * li;
                inpS[g][3] = dz * li;
            }
        }
        __syncthreads();

        // ---- Phase A2: beta[16] = cut * (h @ W_beta) ----
        if (tid < PPC * F1) {
            const int g2 = tid >> 4, j = tid & 15;
            float acc = 0.f;
            #pragma unroll
            for (int kk = 0; kk < F0; ++kk) acc += hS[g2][kk] * wbS[kk * F1 + j];
            betaS[g2][j] = acc * cutS[g2];
        }
        __syncthreads();

        // ---- Phase B: stream FEAT with float4 stores ----
        #pragma unroll
        for (int po = 0; po < PPC; po += 4) {
            const int p = po + q;
            const int e = e0 + p;
            const size_t base = ((size_t)n * N_NB + e) * FEAT + f0;
            float4 gam = {0.f, 0.f, 0.f, 0.f};
            #pragma unroll
            for (int j = 0; j < F1; ++j) {
                const float b = betaS[p][j];
                gam.x += b * wg4[j].x;
                gam.y += b * wg4[j].y;
                gam.z += b * wg4[j].z;
                gam.w += b * wg4[j].w;
            }
            const float i0 = inpS[p][0], i1 = inpS[p][1];
            const float i2 = inpS[p][2], i3 = inpS[p][3];
            float4 ed;
            ed.x = i0 * we4[0].x + i1 * we4[1].x + i2 * we4[2].x + i3 * we4[3].x + zb4.x;
            ed.y = i0 * we4[0].y + i1 * we4[1].y + i2 * we4[2].y + i3 * we4[3].y + zb4.y;
            ed.z = i0 * we4[0].z + i1 * we4[1].z + i2 * we4[2].z + i3 * we4[3].z + zb4.z;
            ed.w = i0 * we4[0].w + i1 * we4[1].w + i2 * we4[2].w + i3 * we4[3].w + zb4.w;
            *reinterpret_cast<float4*>(&gamma_out[base]) = gam;
            *reinterpret_cast<float4*>(&edge_out[base])  = ed;
        }
        __syncthreads();
    }
}

extern "C" void kernel_launch(void* const* d_in, const int* in_sizes, int n_in,
                              void* d_out, int out_size, void* d_ws, size_t ws_size,
                              hipStream_t stream) {
    const float* r_nb_ne    = (const float*)d_in[0];
    const float* R          = (const float*)d_in[1];
    const float* ne_scales  = (const float*)d_in[2];
    const float* ne_kernel  = (const float*)d_in[3];
    const float* ne_bias    = (const float*)d_in[4];
    const float* env_weight = (const float*)d_in[5];
    const float* W_beta     = (const float*)d_in[6];
    const float* W_gamma    = (const float*)d_in[7];
    const float* W_edge     = (const float*)d_in[8];
    const float* b_edge     = (const float*)d_in[9];
    const float* z_n        = (const float*)d_in[10];
    float* out = (float*)d_out;

    moon_fused_kernel<<<NBLOCKS, 256, 0, stream>>>(
        r_nb_ne, R, ne_scales, ne_kernel, ne_bias, env_weight,
        W_beta, W_gamma, W_edge, b_edge, z_n, out);
}

// Round 2
// 142.007 us; speedup vs baseline: 1.1292x; 1.1292x over previous
//
#include <hip/hip_runtime.h>
#include <math.h>

#define N_NUC 256
#define N_NB  1024
#define N_ENV 8
#define F0    32
#define F1    16
#define FEAT  256
#define CUTOFF 5.0f

// wave-autonomous: 8192 waves, 32 pairs/wave, 2 pairs per iteration
constexpr int PAIRS_PER_WAVE = 32;
constexpr int ITERS = PAIRS_PER_WAVE / 2;              // 16
constexpr int NBLOCKS = (N_NUC * N_NB) / PAIRS_PER_WAVE / 4;  // 2048 blocks x 4 waves

__device__ __forceinline__ float rl(float x, int i) {
    // SGPR broadcast from a compile-time lane index; no LDS, no barrier
    return __int_as_float(__builtin_amdgcn_readlane(__float_as_int(x), i));
}

__global__ __launch_bounds__(256) void moon_fused_kernel(
    const float* __restrict__ r_nb_ne,   // (256,1024,3)
    const float* __restrict__ R,         // (256,3)
    const float* __restrict__ ne_scales, // (256,8)
    const float* __restrict__ ne_kernel, // (256,4,32)
    const float* __restrict__ ne_bias,   // (256,32)
    const float* __restrict__ env_weight,// (8,32)
    const float* __restrict__ W_beta,    // (32,16)
    const float* __restrict__ W_gamma,   // (16,256)
    const float* __restrict__ W_edge,    // (4,256)
    const float* __restrict__ b_edge,    // (256)
    const float* __restrict__ z_n,       // (256,256)
    float* __restrict__ out)
{
    const int tid  = threadIdx.x;
    const int lane = tid & 63;
    const int wid  = tid >> 6;
    const int w    = blockIdx.x * 4 + wid;     // global wave id, 0..8191
    const int n    = w >> 5;                   // 32 waves per nucleus
    const int e00  = (w & 31) * PAIRS_PER_WAVE;
    const int k    = lane & 31;                // filter-channel index (phase A)
    const int ph   = lane >> 5;                // pair-half 0/1
    const int j    = lane & 15;                // beta column (phase A2)
    const int f0   = lane * 4;                 // FEAT slice (phase B)

    // ---- per-wave hoisted registers ----
    const float Rx = R[n * 3 + 0], Ry = R[n * 3 + 1], Rz = R[n * 3 + 2];
    const float K0 = ne_kernel[n * 128 + 0 * 32 + k];
    const float K1 = ne_kernel[n * 128 + 1 * 32 + k];
    const float K2 = ne_kernel[n * 128 + 2 * 32 + k];
    const float K3 = ne_kernel[n * 128 + 3 * 32 + k];
    const float bk = ne_bias[n * 32 + k];
    float ew[N_ENV], sc[N_ENV];
    #pragma unroll
    for (int v = 0; v < N_ENV; ++v) ew[v] = env_weight[v * 32 + k];
    #pragma unroll
    for (int v = 0; v < N_ENV; ++v) sc[v] = ne_scales[n * N_ENV + v];

    float wb_col[F0];                          // W_beta column j, per lane
    #pragma unroll
    for (int kk = 0; kk < F0; ++kk) wb_col[kk] = W_beta[kk * F1 + j];

    float4 wg4[F1];
    #pragma unroll
    for (int jj = 0; jj < F1; ++jj)
        wg4[jj] = *reinterpret_cast<const float4*>(&W_gamma[jj * FEAT + f0]);
    float4 we4[4];
    #pragma unroll
    for (int c = 0; c < 4; ++c)
        we4[c] = *reinterpret_cast<const float4*>(&W_edge[c * FEAT + f0]);
    float4 zb4 = *reinterpret_cast<const float4*>(&z_n[n * FEAT + f0]);
    {
        float4 b4 = *reinterpret_cast<const float4*>(&b_edge[f0]);
        zb4.x += b4.x; zb4.y += b4.y; zb4.z += b4.z; zb4.w += b4.w;
    }

    float* __restrict__ gamma_out = out;
    float* __restrict__ edge_out  = out + (size_t)N_NUC * N_NB * FEAT;

    // ---- prefetch iteration 0's electron position ----
    float rx, ry, rz;
    {
        const size_t pr = ((size_t)n * N_NB + e00 + ph) * 3;
        rx = r_nb_ne[pr + 0]; ry = r_nb_ne[pr + 1]; rz = r_nb_ne[pr + 2];
    }

    for (int it = 0; it < ITERS; ++it) {
        const float cx = rx, cy = ry, cz = rz;
        if (it + 1 < ITERS) {
            const size_t pr = ((size_t)n * N_NB + e00 + (it + 1) * 2 + ph) * 3;
            rx = r_nb_ne[pr + 0]; ry = r_nb_ne[pr + 1]; rz = r_nb_ne[pr + 2];
        }

        // ---- Phase A: per-(pair,k) filter value; lanes 0-31 pair0, 32-63 pair1
        const float dx = cx - Rx, dy = cy - Ry, dz = cz - Rz;
        const float d  = sqrtf(dx * dx + dy * dy + dz * dz);
        float env = 0.f;
        #pragma unroll
        for (int v = 0; v < N_ENV; ++v) env += __expf(-d * sc[v]) * ew[v];
        const float pre = d * K0 + dx * K1 + dy * K2 + dz * K3 + bk;
        // tanh via exp: exact at +-inf, ~1e-6 rel error
        const float ex  = __expf(2.f * pre);
        const float hv  = (1.f - __fdividef(2.f, ex + 1.f)) * env;

        const float xcv = d * (1.0f / CUTOFF);
        const float om  = 1.0f - xcv;
        const float cut = (xcv < 1.0f) ? om * om * (1.0f + 2.0f * xcv) : 0.0f;
        const float l   = log1pf(d);
        const float li  = __fdividef(l, d);
        const float i1  = dx * li, i2 = dy * li, i3 = dz * li;

        // ---- Phase A2: beta_j for both pairs via SGPR broadcasts ----
        float acc0 = 0.f, acc1 = 0.f;
        #pragma unroll
        for (int kk = 0; kk < F0; ++kk) {
            const float s0 = rl(hv, kk);
            const float s1 = rl(hv, kk + 32);
            acc0 += s0 * wb_col[kk];
            acc1 += s1 * wb_col[kk];
        }
        const float cut0 = rl(cut, 0), cut1 = rl(cut, 32);
        // lane holds beta for (p=(lane>>4)&1, j=lane&15); lanes 32-63 duplicate
        const float betab = ((lane >> 4) & 1) ? acc1 * cut1 : acc0 * cut0;

        // ---- Phase B: stream FEAT for both pairs, float4 stores ----
        #pragma unroll
        for (int p = 0; p < 2; ++p) {
            const int ep = e00 + it * 2 + p;
            const size_t base = ((size_t)n * N_NB + ep) * FEAT + f0;
            float4 gam = {0.f, 0.f, 0.f, 0.f};
            #pragma unroll
            for (int jj = 0; jj < F1; ++jj) {
                const float b = rl(betab, p * 16 + jj);
                gam.x += b * wg4[jj].x;
                gam.y += b * wg4[jj].y;
                gam.z += b * wg4[jj].z;
                gam.w += b * wg4[jj].w;
            }
            const float i0s = rl(l,  p * 32);
            const float i1s = rl(i1, p * 32);
            const float i2s = rl(i2, p * 32);
            const float i3s = rl(i3, p * 32);
            float4 ed;
            ed.x = i0s * we4[0].x + i1s * we4[1].x + i2s * we4[2].x + i3s * we4[3].x + zb4.x;
            ed.y = i0s * we4[0].y + i1s * we4[1].y + i2s * we4[2].y + i3s * we4[3].y + zb4.y;
            ed.z = i0s * we4[0].z + i1s * we4[1].z + i2s * we4[2].z + i3s * we4[3].z + zb4.z;
            ed.w = i0s * we4[0].w + i1s * we4[1].w + i2s * we4[2].w + i3s * we4[3].w + zb4.w;
            *reinterpret_cast<float4*>(&gamma_out[base]) = gam;
            *reinterpret_cast<float4*>(&edge_out[base])  = ed;
        }
    }
}

extern "C" void kernel_launch(void* const* d_in, const int* in_sizes, int n_in,
                              void* d_out, int out_size, void* d_ws, size_t ws_size,
                              hipStream_t stream) {
    const float* r_nb_ne    = (const float*)d_in[0];
    const float* R          = (const float*)d_in[1];
    const float* ne_scales  = (const float*)d_in[2];
    const float* ne_kernel  = (const float*)d_in[3];
    const float* ne_bias    = (const float*)d_in[4];
    const float* env_weight = (const float*)d_in[5];
    const float* W_beta     = (const float*)d_in[6];
    const float* W_gamma    = (const float*)d_in[7];
    const float* W_edge     = (const float*)d_in[8];
    const float* b_edge     = (const float*)d_in[9];
    const float* z_n        = (const float*)d_in[10];
    float* out = (float*)d_out;

    moon_fused_kernel<<<NBLOCKS, 256, 0, stream>>>(
        r_nb_ne, R, ne_scales, ne_kernel, ne_bias, env_weight,
        W_beta, W_gamma, W_edge, b_edge, z_n, out);
}